// Round 1
// baseline (1803.544 us; speedup 1.0000x reference)
//
#include <hip/hip_runtime.h>

#define N_NODES 100000
#define N_GRAPHS 64
#define BN_EPS 1e-5

// ---------------- degree ----------------
__global__ void deg_kernel(const int* __restrict__ dst, float* __restrict__ deg, int E) {
    int i = blockIdx.x * blockDim.x + threadIdx.x;
    if (i < E) atomicAdd(&deg[dst[i]], 1.0f);
}

// ---------------- edge scatter: agg[dst] += x[src] ----------------
template<int F>
__global__ void scatter_kernel(const float* __restrict__ x, const int* __restrict__ src,
                               const int* __restrict__ dst, float* __restrict__ agg, int E) {
    long long idx = (long long)blockIdx.x * blockDim.x + threadIdx.x;
    long long total = (long long)E * F;
    if (idx >= total) return;
    int e = (int)(idx / F);
    int f = (int)(idx & (F - 1));
    float v = x[(long long)src[e] * F + f];
    atomicAdd(&agg[(long long)dst[e] * F + f], v);
}

// ---------------- fused SAGE linear: h = (agg/deg)@Wl + bl + x@Wr ----------------
template<int DIN, int DOUT>
__global__ void linear_kernel(const float* __restrict__ xin, const float* __restrict__ agg,
                              const float* __restrict__ deg,
                              const float* __restrict__ Wl, const float* __restrict__ bl,
                              const float* __restrict__ Wr, float* __restrict__ hout, int N) {
    const int NPB = 256 / DOUT;
    int n = blockIdx.x * NPB + threadIdx.y;
    int j = threadIdx.x;
    if (n >= N) return;
    float invd = 1.0f / fmaxf(deg[n], 1.0f);
    const float* __restrict__ arow = agg + (long long)n * DIN;
    const float* __restrict__ xrow = xin + (long long)n * DIN;
    float accA = 0.f, accX = 0.f;
#pragma unroll
    for (int k = 0; k < DIN; ++k) {
        accA += arow[k] * Wl[k * DOUT + j];
        accX += xrow[k] * Wr[k * DOUT + j];
    }
    hout[(long long)n * DOUT + j] = accA * invd + bl[j] + accX;
}

// ---------------- BN stats (sum, sumsq per feature) in fp64 ----------------
template<int F>
__global__ void bn_stats_kernel(const float* __restrict__ h, double* __restrict__ sums, int N) {
    const int R = 256 / F;
    int f = threadIdx.x & (F - 1);
    int r = threadIdx.x / F;
    float s = 0.f, sq = 0.f;
    for (int n = blockIdx.x * R + r; n < N; n += gridDim.x * R) {
        float v = h[(long long)n * F + f];
        s += v; sq += v * v;
    }
    __shared__ float sh[512];
    sh[threadIdx.x] = s;
    sh[256 + threadIdx.x] = sq;
    __syncthreads();
    for (int st = R / 2; st > 0; st >>= 1) {
        if (r < st) {
            sh[threadIdx.x] += sh[threadIdx.x + st * F];
            sh[256 + threadIdx.x] += sh[256 + threadIdx.x + st * F];
        }
        __syncthreads();
    }
    if (r == 0) {
        atomicAdd(&sums[f], (double)sh[f]);
        atomicAdd(&sums[F + f], (double)sh[256 + f]);
    }
}

template<int F>
__global__ void bn_finalize_kernel(const double* __restrict__ sums,
                                   const float* __restrict__ gamma, const float* __restrict__ beta,
                                   float* __restrict__ scale, float* __restrict__ shift, int N) {
    int f = threadIdx.x;
    if (f >= F) return;
    double mu  = sums[f] / (double)N;
    double var = sums[F + f] / (double)N - mu * mu;
    if (var < 0.0) var = 0.0;
    double sc = (double)gamma[f] / sqrt(var + BN_EPS);
    scale[f] = (float)sc;
    shift[f] = (float)((double)beta[f] - mu * sc);
}

template<int F>
__global__ void bn_apply_kernel(float* __restrict__ h, const float* __restrict__ scale,
                                const float* __restrict__ shift, int total) {
    int i = blockIdx.x * blockDim.x + threadIdx.x;
    if (i >= total) return;
    int f = i & (F - 1);
    float v = h[i] * scale[f] + shift[f];
    h[i] = fmaxf(v, 0.f);
}

// ---------------- per-graph mean pool (batch is sorted -> binary search) ----------------
__global__ void pool_kernel(const float* __restrict__ h, const int* __restrict__ batch,
                            float* __restrict__ pooled, int N) {
    int g = blockIdx.x;
    int lo = 0, hi = N;
    while (lo < hi) { int mid = (lo + hi) >> 1; if (batch[mid] < g) lo = mid + 1; else hi = mid; }
    int start = lo;
    hi = N;
    while (lo < hi) { int mid = (lo + hi) >> 1; if (batch[mid] < g + 1) lo = mid + 1; else hi = mid; }
    int end = lo;
    int f = threadIdx.x;  // 128 features
    float s = 0.f;
    for (int n = start; n < end; ++n) s += h[(long long)n * 128 + f];
    float cnt = fmaxf((float)(end - start), 1.0f);
    pooled[g * 128 + f] = s / cnt;
}

// ---------------- head MLP: relu(pooled@Wf1+bf1)@Wf2+bf2 ----------------
__global__ void mlp_kernel(const float* __restrict__ pooled,
                           const float* __restrict__ Wf1, const float* __restrict__ bf1,
                           const float* __restrict__ Wf2, const float* __restrict__ bf2,
                           float* __restrict__ out) {
    int g = blockIdx.x;
    int j = threadIdx.x;  // 64 hidden
    float hacc = bf1[j];
#pragma unroll 8
    for (int k = 0; k < 128; ++k) hacc += pooled[g * 128 + k] * Wf1[k * 64 + j];
    hacc = fmaxf(hacc, 0.f) * Wf2[j];
    for (int off = 32; off > 0; off >>= 1) hacc += __shfl_down(hacc, off);
    if (j == 0) out[g] = hacc + bf2[0];
}

extern "C" void kernel_launch(void* const* d_in, const int* in_sizes, int n_in,
                              void* d_out, int out_size, void* d_ws, size_t ws_size,
                              hipStream_t stream) {
    const float* x     = (const float*)d_in[0];
    const int*   ei    = (const int*)d_in[1];
    const int*   batch = (const int*)d_in[2];
    const float *Wl1=(const float*)d_in[3],  *bl1=(const float*)d_in[4],  *Wr1=(const float*)d_in[5];
    const float *g1 =(const float*)d_in[6],  *be1=(const float*)d_in[7];
    const float *Wl2=(const float*)d_in[8],  *bl2=(const float*)d_in[9],  *Wr2=(const float*)d_in[10];
    const float *g2 =(const float*)d_in[11], *be2=(const float*)d_in[12];
    const float *Wl3=(const float*)d_in[13], *bl3=(const float*)d_in[14], *Wr3=(const float*)d_in[15];
    const float *g3 =(const float*)d_in[16], *be3=(const float*)d_in[17];
    const float *Wf1=(const float*)d_in[18], *bf1=(const float*)d_in[19];
    const float *Wf2=(const float*)d_in[20], *bf2=(const float*)d_in[21];

    const int N = N_NODES;
    const int E = in_sizes[1] / 2;
    const int* src = ei;
    const int* dst = ei + E;

    char* ws = (char*)d_ws;
    float*  deg    = (float*)(ws + 0);                  // 400,000 B
    float*  agg    = (float*)(ws + 400000);             // 25,600,000 B (max N*64*4)
    float*  bufA   = (float*)(ws + 26000000);           // 51,200,000 B (N*128*4)
    float*  bufB   = (float*)(ws + 77200000);           // 25,600,000 B (N*64*4)
    double* sums   = (double*)(ws + 102800000);         // 2048 B (128 sum + 128 sumsq)
    float*  scale  = (float*)(ws + 102802048);          // 512 B
    float*  shift  = (float*)(ws + 102802560);          // 512 B
    float*  pooled = (float*)(ws + 102803072);          // 32,768 B

    // degree (shared by all three layers)
    hipMemsetAsync(deg, 0, (size_t)N * 4, stream);
    deg_kernel<<<(E + 255) / 256, 256, 0, stream>>>(dst, deg, E);

    // ---- layer 1: 2 -> 32, in x, out bufA ----
    hipMemsetAsync(agg, 0, (size_t)N * 2 * 4, stream);
    hipMemsetAsync(sums, 0, 2048, stream);
    scatter_kernel<2><<<(int)(((long long)E * 2 + 255) / 256), 256, 0, stream>>>(x, src, dst, agg, E);
    linear_kernel<2, 32><<<N / 8, dim3(32, 8), 0, stream>>>(x, agg, deg, Wl1, bl1, Wr1, bufA, N);
    bn_stats_kernel<32><<<256, 256, 0, stream>>>(bufA, sums, N);
    bn_finalize_kernel<32><<<1, 32, 0, stream>>>(sums, g1, be1, scale, shift, N);
    bn_apply_kernel<32><<<(N * 32 + 255) / 256, 256, 0, stream>>>(bufA, scale, shift, N * 32);

    // ---- layer 2: 32 -> 64, in bufA, out bufB ----
    hipMemsetAsync(agg, 0, (size_t)N * 32 * 4, stream);
    hipMemsetAsync(sums, 0, 2048, stream);
    scatter_kernel<32><<<(int)(((long long)E * 32 + 255) / 256), 256, 0, stream>>>(bufA, src, dst, agg, E);
    linear_kernel<32, 64><<<N / 4, dim3(64, 4), 0, stream>>>(bufA, agg, deg, Wl2, bl2, Wr2, bufB, N);
    bn_stats_kernel<64><<<256, 256, 0, stream>>>(bufB, sums, N);
    bn_finalize_kernel<64><<<1, 64, 0, stream>>>(sums, g2, be2, scale, shift, N);
    bn_apply_kernel<64><<<(N * 64 + 255) / 256, 256, 0, stream>>>(bufB, scale, shift, N * 64);

    // ---- layer 3: 64 -> 128, in bufB, out bufA ----
    hipMemsetAsync(agg, 0, (size_t)N * 64 * 4, stream);
    hipMemsetAsync(sums, 0, 2048, stream);
    scatter_kernel<64><<<(int)(((long long)E * 64 + 255) / 256), 256, 0, stream>>>(bufB, src, dst, agg, E);
    linear_kernel<64, 128><<<N / 2, dim3(128, 2), 0, stream>>>(bufB, agg, deg, Wl3, bl3, Wr3, bufA, N);
    bn_stats_kernel<128><<<256, 256, 0, stream>>>(bufA, sums, N);
    bn_finalize_kernel<128><<<1, 128, 0, stream>>>(sums, g3, be3, scale, shift, N);
    bn_apply_kernel<128><<<(N * 128 + 255) / 256, 256, 0, stream>>>(bufA, scale, shift, N * 128);

    // ---- pool + head ----
    pool_kernel<<<N_GRAPHS, 128, 0, stream>>>(bufA, batch, pooled, N);
    mlp_kernel<<<N_GRAPHS, 64, 0, stream>>>(pooled, Wf1, bf1, Wf2, bf2, (float*)d_out);
}

// Round 2
// 1128.953 us; speedup vs baseline: 1.5975x; 1.5975x over previous
//
#include <hip/hip_runtime.h>

#define N_NODES 100000
#define N_GRAPHS 64
#define BN_EPS 1e-5

// ---------------- in-degree (int) ----------------
__global__ void degi_kernel(const int* __restrict__ dst, int* __restrict__ degi, int E) {
    int i = blockIdx.x * blockDim.x + threadIdx.x;
    if (i < E) atomicAdd(&degi[dst[i]], 1);
}

// ---------------- exclusive scan of degi -> offs (hierarchical) ----------------
// scan1: each block handles 1024 elems (256 thr x 4), writes local-exclusive to offs, block sum to bsums
__global__ void scan1_kernel(const int* __restrict__ degi, int* __restrict__ offs,
                             int* __restrict__ bsums, int N) {
    __shared__ int sh[256];
    int t = threadIdx.x;
    int base = blockIdx.x * 1024;
    int v[4]; int s = 0;
#pragma unroll
    for (int k = 0; k < 4; ++k) {
        int idx = base + t * 4 + k;
        v[k] = (idx < N) ? degi[idx] : 0;
        s += v[k];
    }
    sh[t] = s;
    __syncthreads();
    for (int st = 1; st < 256; st <<= 1) {
        int val = (t >= st) ? sh[t - st] : 0;
        __syncthreads();
        if (t >= st) sh[t] += val;
        __syncthreads();
    }
    int excl = (t > 0) ? sh[t - 1] : 0;
    if (t == 255) bsums[blockIdx.x] = sh[255];
    int run = excl;
#pragma unroll
    for (int k = 0; k < 4; ++k) {
        int idx = base + t * 4 + k;
        if (idx < N) offs[idx] = run;
        run += v[k];
    }
}

// scan2: serial exclusive scan of block sums (~98 elems)
__global__ void scan2_kernel(int* __restrict__ bsums, int nb) {
    if (blockIdx.x == 0 && threadIdx.x == 0) {
        int run = 0;
        for (int i = 0; i < nb; ++i) { int v = bsums[i]; bsums[i] = run; run += v; }
    }
}

// scan3: add block offset, init cursor, set offs[N]=E
__global__ void scan3_kernel(int* __restrict__ offs, const int* __restrict__ bsums,
                             int* __restrict__ cursor, int N, int E) {
    int i = blockIdx.x * blockDim.x + threadIdx.x;
    if (i < N) {
        int v = offs[i] + bsums[i >> 10];
        offs[i] = v;
        cursor[i] = v;
    }
    if (i == 0) offs[N] = E;
}

// fill: nbr sorted by dst
__global__ void fill_kernel(const int* __restrict__ src, const int* __restrict__ dst,
                            int* __restrict__ cursor, int* __restrict__ nbr, int E) {
    int e = blockIdx.x * blockDim.x + threadIdx.x;
    if (e < E) {
        int p = atomicAdd(&cursor[dst[e]], 1);
        nbr[p] = src[e];
    }
}

// ---------------- CSR gather aggregation ----------------
// F=2 special case: one thread per node, float2
__global__ void agg2_kernel(const float2* __restrict__ x, const int* __restrict__ offs,
                            const int* __restrict__ nbr, float2* __restrict__ agg, int N) {
    int n = blockIdx.x * blockDim.x + threadIdx.x;
    if (n >= N) return;
    int beg = offs[n], end = offs[n + 1];
    float ax = 0.f, ay = 0.f;
    for (int j = beg; j < end; ++j) {
        float2 v = x[nbr[j]];
        ax += v.x; ay += v.y;
    }
    agg[n] = make_float2(ax, ay);
}

// F in {32,64}: FV=F/4 lanes per node, float4 gathers
template<int F>
__global__ void agg_csr_v4(const float4* __restrict__ x, const int* __restrict__ offs,
                           const int* __restrict__ nbr, float4* __restrict__ agg, int N) {
    const int FV = F / 4;
    const int NPB = 256 / FV;
    int n = blockIdx.x * NPB + threadIdx.y;
    if (n >= N) return;
    int f = threadIdx.x;
    int beg = offs[n], end = offs[n + 1];
    float4 acc = {0.f, 0.f, 0.f, 0.f};
    for (int j = beg; j < end; ++j) {
        int s = nbr[j];
        float4 v = x[(long long)s * FV + f];
        acc.x += v.x; acc.y += v.y; acc.z += v.z; acc.w += v.w;
    }
    agg[(long long)n * FV + f] = acc;
}

// ---------------- fused SAGE linear: h = (agg/deg)@Wl + bl + x@Wr ----------------
template<int DIN, int DOUT>
__global__ void linear_kernel(const float* __restrict__ xin, const float* __restrict__ agg,
                              const int* __restrict__ degi,
                              const float* __restrict__ Wl, const float* __restrict__ bl,
                              const float* __restrict__ Wr, float* __restrict__ hout, int N) {
    const int NPB = 256 / DOUT;
    int n = blockIdx.x * NPB + threadIdx.y;
    int j = threadIdx.x;
    if (n >= N) return;
    float invd = 1.0f / fmaxf((float)degi[n], 1.0f);
    const float* __restrict__ arow = agg + (long long)n * DIN;
    const float* __restrict__ xrow = xin + (long long)n * DIN;
    float accA = 0.f, accX = 0.f;
#pragma unroll
    for (int k = 0; k < DIN; ++k) {
        accA += arow[k] * Wl[k * DOUT + j];
        accX += xrow[k] * Wr[k * DOUT + j];
    }
    hout[(long long)n * DOUT + j] = accA * invd + bl[j] + accX;
}

// ---------------- BN stats (sum, sumsq per feature), fp64 accumulation ----------------
template<int F>
__global__ void bn_stats_kernel(const float* __restrict__ h, double* __restrict__ sums, int N) {
    const int R = 256 / F;
    int f = threadIdx.x & (F - 1);
    int r = threadIdx.x / F;
    float s = 0.f, sq = 0.f;
    for (int n = blockIdx.x * R + r; n < N; n += gridDim.x * R) {
        float v = h[(long long)n * F + f];
        s += v; sq += v * v;
    }
    __shared__ float sh[512];
    sh[threadIdx.x] = s;
    sh[256 + threadIdx.x] = sq;
    __syncthreads();
    for (int st = R / 2; st > 0; st >>= 1) {
        if (r < st) {
            sh[threadIdx.x] += sh[threadIdx.x + st * F];
            sh[256 + threadIdx.x] += sh[256 + threadIdx.x + st * F];
        }
        __syncthreads();
    }
    if (r == 0) {
        atomicAdd(&sums[f], (double)sh[f]);
        atomicAdd(&sums[F + f], (double)sh[256 + f]);
    }
}

template<int F>
__global__ void bn_finalize_kernel(const double* __restrict__ sums,
                                   const float* __restrict__ gamma, const float* __restrict__ beta,
                                   float* __restrict__ scale, float* __restrict__ shift, int N) {
    int f = threadIdx.x;
    if (f >= F) return;
    double mu  = sums[f] / (double)N;
    double var = sums[F + f] / (double)N - mu * mu;
    if (var < 0.0) var = 0.0;
    double sc = (double)gamma[f] / sqrt(var + BN_EPS);
    scale[f] = (float)sc;
    shift[f] = (float)((double)beta[f] - mu * sc);
}

// float4 BN+ReLU apply
template<int F>
__global__ void bn_apply_v4(float4* __restrict__ h, const float4* __restrict__ scale,
                            const float4* __restrict__ shift, int total4) {
    int i = blockIdx.x * blockDim.x + threadIdx.x;
    if (i >= total4) return;
    int fv = i & (F / 4 - 1);
    float4 v = h[i];
    float4 sc = scale[fv];
    float4 sf = shift[fv];
    v.x = fmaxf(v.x * sc.x + sf.x, 0.f);
    v.y = fmaxf(v.y * sc.y + sf.y, 0.f);
    v.z = fmaxf(v.z * sc.z + sf.z, 0.f);
    v.w = fmaxf(v.w * sc.w + sf.w, 0.f);
    h[i] = v;
}

// ---------------- parallel pool: chunked run-length accumulate over sorted batch ----------------
__global__ void pool_partial(const float* __restrict__ h, const int* __restrict__ batch,
                             float* __restrict__ pooled, int N) {
    const int CH = 256;
    int n0 = blockIdx.x * CH;
    if (n0 >= N) return;
    int n1 = min(n0 + CH, N);
    int f = threadIdx.x;  // 128
    int g = batch[n0];
    float acc = 0.f;
    for (int n = n0; n < n1; ++n) {
        int bg = batch[n];
        if (bg != g) {
            atomicAdd(&pooled[g * 128 + f], acc);
            acc = 0.f;
            g = bg;
        }
        acc += h[(long long)n * 128 + f];
    }
    atomicAdd(&pooled[g * 128 + f], acc);
}

__global__ void pool_finalize(float* __restrict__ pooled, const int* __restrict__ batch, int N) {
    int g = blockIdx.x;
    int f = threadIdx.x;
    int lo = 0, hi = N;
    while (lo < hi) { int m = (lo + hi) >> 1; if (batch[m] < g) lo = m + 1; else hi = m; }
    int start = lo;
    hi = N;
    while (lo < hi) { int m = (lo + hi) >> 1; if (batch[m] < g + 1) lo = m + 1; else hi = m; }
    int cnt = lo - start;
    pooled[g * 128 + f] /= fmaxf((float)cnt, 1.0f);
}

// ---------------- head MLP ----------------
__global__ void mlp_kernel(const float* __restrict__ pooled,
                           const float* __restrict__ Wf1, const float* __restrict__ bf1,
                           const float* __restrict__ Wf2, const float* __restrict__ bf2,
                           float* __restrict__ out) {
    int g = blockIdx.x;
    int j = threadIdx.x;  // 64 hidden
    float hacc = bf1[j];
#pragma unroll 8
    for (int k = 0; k < 128; ++k) hacc += pooled[g * 128 + k] * Wf1[k * 64 + j];
    hacc = fmaxf(hacc, 0.f) * Wf2[j];
    for (int off = 32; off > 0; off >>= 1) hacc += __shfl_down(hacc, off);
    if (j == 0) out[g] = hacc + bf2[0];
}

extern "C" void kernel_launch(void* const* d_in, const int* in_sizes, int n_in,
                              void* d_out, int out_size, void* d_ws, size_t ws_size,
                              hipStream_t stream) {
    const float* x     = (const float*)d_in[0];
    const int*   ei    = (const int*)d_in[1];
    const int*   batch = (const int*)d_in[2];
    const float *Wl1=(const float*)d_in[3],  *bl1=(const float*)d_in[4],  *Wr1=(const float*)d_in[5];
    const float *g1 =(const float*)d_in[6],  *be1=(const float*)d_in[7];
    const float *Wl2=(const float*)d_in[8],  *bl2=(const float*)d_in[9],  *Wr2=(const float*)d_in[10];
    const float *g2 =(const float*)d_in[11], *be2=(const float*)d_in[12];
    const float *Wl3=(const float*)d_in[13], *bl3=(const float*)d_in[14], *Wr3=(const float*)d_in[15];
    const float *g3 =(const float*)d_in[16], *be3=(const float*)d_in[17];
    const float *Wf1=(const float*)d_in[18], *bf1=(const float*)d_in[19];
    const float *Wf2=(const float*)d_in[20], *bf2=(const float*)d_in[21];

    const int N = N_NODES;
    const int E = in_sizes[1] / 2;
    const int* src = ei;
    const int* dst = ei + E;

    // ---- workspace layout (256B-aligned) ----
    char* ws = (char*)d_ws;
    size_t off = 0;
    auto salloc = [&](size_t bytes) {
        void* p = ws + off;
        off += (bytes + 255) & ~(size_t)255;
        return p;
    };
    int*    degi   = (int*)   salloc((size_t)N * 4);
    int*    offs   = (int*)   salloc((size_t)(N + 1) * 4);
    int*    cursor = (int*)   salloc((size_t)N * 4);
    int*    bsums  = (int*)   salloc(512);
    int*    nbr    = (int*)   salloc((size_t)E * 4);          // 6.4 MB
    float*  aggb   = (float*) salloc((size_t)N * 64 * 4);     // 25.6 MB (max agg)
    float*  bufA   = (float*) salloc((size_t)N * 128 * 4);    // 51.2 MB (h1 then h3)
    float*  bufB   = (float*) salloc((size_t)N * 64 * 4);     // 25.6 MB (h2)
    double* sums   = (double*)salloc(768 * 8);                // 3 layers x (F sums + F sumsq)
    float*  scale  = (float*) salloc(512);
    float*  shift  = (float*) salloc(512);
    float*  pooled = (float*) salloc((size_t)N_GRAPHS * 128 * 4);
    (void)ws_size;

    double* sums1 = sums, *sums2 = sums + 256, *sums3 = sums + 512;

    // ---- zero init ----
    hipMemsetAsync(degi, 0, (size_t)N * 4, stream);
    hipMemsetAsync(sums, 0, 768 * 8, stream);
    hipMemsetAsync(pooled, 0, (size_t)N_GRAPHS * 128 * 4, stream);

    // ---- CSR build (by dst) ----
    const int nb = (N + 1023) / 1024;  // scan blocks
    degi_kernel<<<(E + 255) / 256, 256, 0, stream>>>(dst, degi, E);
    scan1_kernel<<<nb, 256, 0, stream>>>(degi, offs, bsums, N);
    scan2_kernel<<<1, 64, 0, stream>>>(bsums, nb);
    scan3_kernel<<<(N + 255) / 256, 256, 0, stream>>>(offs, bsums, cursor, N, E);
    fill_kernel<<<(E + 255) / 256, 256, 0, stream>>>(src, dst, cursor, nbr, E);

    // ---- layer 1: 2 -> 32, in x, out bufA ----
    agg2_kernel<<<(N + 255) / 256, 256, 0, stream>>>((const float2*)x, offs, nbr, (float2*)aggb, N);
    linear_kernel<2, 32><<<N / 8, dim3(32, 8), 0, stream>>>(x, aggb, degi, Wl1, bl1, Wr1, bufA, N);
    bn_stats_kernel<32><<<256, 256, 0, stream>>>(bufA, sums1, N);
    bn_finalize_kernel<32><<<1, 32, 0, stream>>>(sums1, g1, be1, scale, shift, N);
    bn_apply_v4<32><<<(N * 32 / 4 + 255) / 256, 256, 0, stream>>>((float4*)bufA, (const float4*)scale, (const float4*)shift, N * 32 / 4);

    // ---- layer 2: 32 -> 64, in bufA, out bufB ----
    agg_csr_v4<32><<<(N + 31) / 32, dim3(8, 32), 0, stream>>>((const float4*)bufA, offs, nbr, (float4*)aggb, N);
    linear_kernel<32, 64><<<N / 4, dim3(64, 4), 0, stream>>>(bufA, aggb, degi, Wl2, bl2, Wr2, bufB, N);
    bn_stats_kernel<64><<<256, 256, 0, stream>>>(bufB, sums2, N);
    bn_finalize_kernel<64><<<1, 64, 0, stream>>>(sums2, g2, be2, scale, shift, N);
    bn_apply_v4<64><<<(N * 64 / 4 + 255) / 256, 256, 0, stream>>>((float4*)bufB, (const float4*)scale, (const float4*)shift, N * 64 / 4);

    // ---- layer 3: 64 -> 128, in bufB, out bufA (h1 dead) ----
    agg_csr_v4<64><<<(N + 15) / 16, dim3(16, 16), 0, stream>>>((const float4*)bufB, offs, nbr, (float4*)aggb, N);
    linear_kernel<64, 128><<<N / 2, dim3(128, 2), 0, stream>>>(bufB, aggb, degi, Wl3, bl3, Wr3, bufA, N);
    bn_stats_kernel<128><<<256, 256, 0, stream>>>(bufA, sums3, N);
    bn_finalize_kernel<128><<<1, 128, 0, stream>>>(sums3, g3, be3, scale, shift, N);
    bn_apply_v4<128><<<(N * 128 / 4 + 255) / 256, 256, 0, stream>>>((float4*)bufA, (const float4*)scale, (const float4*)shift, N * 128 / 4);

    // ---- pool + head ----
    pool_partial<<<(N + 255) / 256, 128, 0, stream>>>(bufA, batch, pooled, N);
    pool_finalize<<<N_GRAPHS, 128, 0, stream>>>(pooled, batch, N);
    mlp_kernel<<<N_GRAPHS, 64, 0, stream>>>(pooled, Wf1, bf1, Wf2, bf2, (float*)d_out);
}

// Round 3
// 909.667 us; speedup vs baseline: 1.9826x; 1.2411x over previous
//
#include <hip/hip_runtime.h>

#define N_NODES 100000
#define N_GRAPHS 64
#define BN_EPS 1e-5

// ---------------- in-degree (int) ----------------
__global__ void degi_kernel(const int* __restrict__ dst, int* __restrict__ degi, int E) {
    int i = blockIdx.x * blockDim.x + threadIdx.x;
    if (i < E) atomicAdd(&degi[dst[i]], 1);
}

// ---------------- exclusive scan of degi -> offs (hierarchical) ----------------
__global__ void scan1_kernel(const int* __restrict__ degi, int* __restrict__ offs,
                             int* __restrict__ bsums, int N) {
    __shared__ int sh[256];
    int t = threadIdx.x;
    int base = blockIdx.x * 1024;
    int v[4]; int s = 0;
#pragma unroll
    for (int k = 0; k < 4; ++k) {
        int idx = base + t * 4 + k;
        v[k] = (idx < N) ? degi[idx] : 0;
        s += v[k];
    }
    sh[t] = s;
    __syncthreads();
    for (int st = 1; st < 256; st <<= 1) {
        int val = (t >= st) ? sh[t - st] : 0;
        __syncthreads();
        if (t >= st) sh[t] += val;
        __syncthreads();
    }
    int excl = (t > 0) ? sh[t - 1] : 0;
    if (t == 255) bsums[blockIdx.x] = sh[255];
    int run = excl;
#pragma unroll
    for (int k = 0; k < 4; ++k) {
        int idx = base + t * 4 + k;
        if (idx < N) offs[idx] = run;
        run += v[k];
    }
}

__global__ void scan2_kernel(int* __restrict__ bsums, int nb) {
    if (blockIdx.x == 0 && threadIdx.x == 0) {
        int run = 0;
        for (int i = 0; i < nb; ++i) { int v = bsums[i]; bsums[i] = run; run += v; }
    }
}

__global__ void scan3_kernel(int* __restrict__ offs, const int* __restrict__ bsums,
                             int* __restrict__ cursor, int N, int E) {
    int i = blockIdx.x * blockDim.x + threadIdx.x;
    if (i < N) {
        int v = offs[i] + bsums[i >> 10];
        offs[i] = v;
        cursor[i] = v;
    }
    if (i == 0) offs[N] = E;
}

__global__ void fill_kernel(const int* __restrict__ src, const int* __restrict__ dst,
                            int* __restrict__ cursor, int* __restrict__ nbr, int E) {
    int e = blockIdx.x * blockDim.x + threadIdx.x;
    if (e < E) {
        int p = atomicAdd(&cursor[dst[e]], 1);
        nbr[p] = src[e];
    }
}

// ---------------- CSR gather aggregation ----------------
__global__ void agg2_kernel(const float2* __restrict__ x, const int* __restrict__ offs,
                            const int* __restrict__ nbr, float2* __restrict__ agg, int N) {
    int n = blockIdx.x * blockDim.x + threadIdx.x;
    if (n >= N) return;
    int beg = offs[n], end = offs[n + 1];
    float ax = 0.f, ay = 0.f;
    for (int j = beg; j < end; ++j) {
        float2 v = x[nbr[j]];
        ax += v.x; ay += v.y;
    }
    agg[n] = make_float2(ax, ay);
}

template<int F>
__global__ void agg_csr_v4(const float4* __restrict__ x, const int* __restrict__ offs,
                           const int* __restrict__ nbr, float4* __restrict__ agg, int N) {
    const int FV = F / 4;
    const int NPB = 256 / FV;
    int n = blockIdx.x * NPB + threadIdx.y;
    if (n >= N) return;
    int f = threadIdx.x;
    int beg = offs[n], end = offs[n + 1];
    float4 acc = {0.f, 0.f, 0.f, 0.f};
    for (int j = beg; j < end; ++j) {
        int s = nbr[j];
        float4 v = x[(long long)s * FV + f];
        acc.x += v.x; acc.y += v.y; acc.z += v.z; acc.w += v.w;
    }
    agg[(long long)n * FV + f] = acc;
}

// ---------------- register-tiled fused SAGE linear ----------------
// h[n] = (agg[n]/deg[n]) @ Wl + bl + x[n] @ Wr
// One node per lane; rows in VGPRs (pre-scaled by invd); weights at
// wave-uniform addresses -> scalar loads; merged accumulator per output.
template<int DIN, int DOUT>
__global__ __launch_bounds__(256)
void linear_rt(const float* __restrict__ xin, const float* __restrict__ agg,
               const int* __restrict__ degi,
               const float* __restrict__ Wl, const float* __restrict__ bl,
               const float* __restrict__ Wr, float* __restrict__ hout, int N) {
    int n = blockIdx.x * 256 + threadIdx.x;
    if (n >= N) return;
    float invd = 1.0f / fmaxf((float)degi[n], 1.0f);
    const float* __restrict__ ar = agg + (size_t)n * DIN;
    const float* __restrict__ xp = xin + (size_t)n * DIN;
    constexpr int KC = (DIN >= 8) ? 8 : DIN;   // k-chunk
    constexpr int JT = 32;                      // j-tile

#pragma unroll 1
    for (int jt = 0; jt < DOUT; jt += JT) {
        float acc[JT];
#pragma unroll
        for (int j = 0; j < JT; ++j) acc[j] = bl[jt + j];

#pragma unroll 1
        for (int kc = 0; kc < DIN; kc += KC) {
            float a[KC], xr[KC];
            if constexpr (KC == 8) {
                float4 v0 = *(const float4*)(ar + kc);
                float4 v1 = *(const float4*)(ar + kc + 4);
                a[0]=v0.x*invd; a[1]=v0.y*invd; a[2]=v0.z*invd; a[3]=v0.w*invd;
                a[4]=v1.x*invd; a[5]=v1.y*invd; a[6]=v1.z*invd; a[7]=v1.w*invd;
                float4 u0 = *(const float4*)(xp + kc);
                float4 u1 = *(const float4*)(xp + kc + 4);
                xr[0]=u0.x; xr[1]=u0.y; xr[2]=u0.z; xr[3]=u0.w;
                xr[4]=u1.x; xr[5]=u1.y; xr[6]=u1.z; xr[7]=u1.w;
            } else {  // KC == 2
                float2 v = *(const float2*)ar;
                a[0] = v.x * invd; a[1] = v.y * invd;
                float2 u = *(const float2*)xp;
                xr[0] = u.x; xr[1] = u.y;
            }
#pragma unroll
            for (int kk = 0; kk < KC; ++kk) {
                const float* __restrict__ wlp = Wl + (size_t)(kc + kk) * DOUT + jt;
                const float* __restrict__ wrp = Wr + (size_t)(kc + kk) * DOUT + jt;
                float av = a[kk], xv = xr[kk];
#pragma unroll
                for (int j = 0; j < JT; ++j)
                    acc[j] += av * wlp[j] + xv * wrp[j];
            }
        }
        float4* __restrict__ op = (float4*)(hout + (size_t)n * DOUT + jt);
#pragma unroll
        for (int j4 = 0; j4 < JT / 4; ++j4)
            op[j4] = make_float4(acc[4*j4], acc[4*j4+1], acc[4*j4+2], acc[4*j4+3]);
    }
}

// ---------------- BN stats (sum, sumsq per feature), fp64 accumulation ----------------
template<int F>
__global__ void bn_stats_kernel(const float* __restrict__ h, double* __restrict__ sums, int N) {
    const int R = 256 / F;
    int f = threadIdx.x & (F - 1);
    int r = threadIdx.x / F;
    float s = 0.f, sq = 0.f;
    for (int n = blockIdx.x * R + r; n < N; n += gridDim.x * R) {
        float v = h[(long long)n * F + f];
        s += v; sq += v * v;
    }
    __shared__ float sh[512];
    sh[threadIdx.x] = s;
    sh[256 + threadIdx.x] = sq;
    __syncthreads();
    for (int st = R / 2; st > 0; st >>= 1) {
        if (r < st) {
            sh[threadIdx.x] += sh[threadIdx.x + st * F];
            sh[256 + threadIdx.x] += sh[256 + threadIdx.x + st * F];
        }
        __syncthreads();
    }
    if (r == 0) {
        atomicAdd(&sums[f], (double)sh[f]);
        atomicAdd(&sums[F + f], (double)sh[256 + f]);
    }
}

template<int F>
__global__ void bn_finalize_kernel(const double* __restrict__ sums,
                                   const float* __restrict__ gamma, const float* __restrict__ beta,
                                   float* __restrict__ scale, float* __restrict__ shift, int N) {
    int f = threadIdx.x;
    if (f >= F) return;
    double mu  = sums[f] / (double)N;
    double var = sums[F + f] / (double)N - mu * mu;
    if (var < 0.0) var = 0.0;
    double sc = (double)gamma[f] / sqrt(var + BN_EPS);
    scale[f] = (float)sc;
    shift[f] = (float)((double)beta[f] - mu * sc);
}

template<int F>
__global__ void bn_apply_v4(float4* __restrict__ h, const float4* __restrict__ scale,
                            const float4* __restrict__ shift, int total4) {
    int i = blockIdx.x * blockDim.x + threadIdx.x;
    if (i >= total4) return;
    int fv = i & (F / 4 - 1);
    float4 v = h[i];
    float4 sc = scale[fv];
    float4 sf = shift[fv];
    v.x = fmaxf(v.x * sc.x + sf.x, 0.f);
    v.y = fmaxf(v.y * sc.y + sf.y, 0.f);
    v.z = fmaxf(v.z * sc.z + sf.z, 0.f);
    v.w = fmaxf(v.w * sc.w + sf.w, 0.f);
    h[i] = v;
}

// ---------------- parallel pool ----------------
__global__ void pool_partial(const float* __restrict__ h, const int* __restrict__ batch,
                             float* __restrict__ pooled, int N) {
    const int CH = 256;
    int n0 = blockIdx.x * CH;
    if (n0 >= N) return;
    int n1 = min(n0 + CH, N);
    int f = threadIdx.x;  // 128
    int g = batch[n0];
    float acc = 0.f;
    for (int n = n0; n < n1; ++n) {
        int bg = batch[n];
        if (bg != g) {
            atomicAdd(&pooled[g * 128 + f], acc);
            acc = 0.f;
            g = bg;
        }
        acc += h[(long long)n * 128 + f];
    }
    atomicAdd(&pooled[g * 128 + f], acc);
}

__global__ void pool_finalize(float* __restrict__ pooled, const int* __restrict__ batch, int N) {
    int g = blockIdx.x;
    int f = threadIdx.x;
    int lo = 0, hi = N;
    while (lo < hi) { int m = (lo + hi) >> 1; if (batch[m] < g) lo = m + 1; else hi = m; }
    int start = lo;
    hi = N;
    while (lo < hi) { int m = (lo + hi) >> 1; if (batch[m] < g + 1) lo = m + 1; else hi = m; }
    int cnt = lo - start;
    pooled[g * 128 + f] /= fmaxf((float)cnt, 1.0f);
}

// ---------------- head MLP ----------------
__global__ void mlp_kernel(const float* __restrict__ pooled,
                           const float* __restrict__ Wf1, const float* __restrict__ bf1,
                           const float* __restrict__ Wf2, const float* __restrict__ bf2,
                           float* __restrict__ out) {
    int g = blockIdx.x;
    int j = threadIdx.x;  // 64 hidden
    float hacc = bf1[j];
#pragma unroll 8
    for (int k = 0; k < 128; ++k) hacc += pooled[g * 128 + k] * Wf1[k * 64 + j];
    hacc = fmaxf(hacc, 0.f) * Wf2[j];
    for (int off = 32; off > 0; off >>= 1) hacc += __shfl_down(hacc, off);
    if (j == 0) out[g] = hacc + bf2[0];
}

extern "C" void kernel_launch(void* const* d_in, const int* in_sizes, int n_in,
                              void* d_out, int out_size, void* d_ws, size_t ws_size,
                              hipStream_t stream) {
    const float* x     = (const float*)d_in[0];
    const int*   ei    = (const int*)d_in[1];
    const int*   batch = (const int*)d_in[2];
    const float *Wl1=(const float*)d_in[3],  *bl1=(const float*)d_in[4],  *Wr1=(const float*)d_in[5];
    const float *g1 =(const float*)d_in[6],  *be1=(const float*)d_in[7];
    const float *Wl2=(const float*)d_in[8],  *bl2=(const float*)d_in[9],  *Wr2=(const float*)d_in[10];
    const float *g2 =(const float*)d_in[11], *be2=(const float*)d_in[12];
    const float *Wl3=(const float*)d_in[13], *bl3=(const float*)d_in[14], *Wr3=(const float*)d_in[15];
    const float *g3 =(const float*)d_in[16], *be3=(const float*)d_in[17];
    const float *Wf1=(const float*)d_in[18], *bf1=(const float*)d_in[19];
    const float *Wf2=(const float*)d_in[20], *bf2=(const float*)d_in[21];

    const int N = N_NODES;
    const int E = in_sizes[1] / 2;
    const int* src = ei;
    const int* dst = ei + E;

    // ---- workspace layout (256B-aligned) ----
    char* ws = (char*)d_ws;
    size_t off = 0;
    auto salloc = [&](size_t bytes) {
        void* p = ws + off;
        off += (bytes + 255) & ~(size_t)255;
        return p;
    };
    int*    degi   = (int*)   salloc((size_t)N * 4);
    int*    offs   = (int*)   salloc((size_t)(N + 1) * 4);
    int*    cursor = (int*)   salloc((size_t)N * 4);
    int*    bsums  = (int*)   salloc(512);
    int*    nbr    = (int*)   salloc((size_t)E * 4);
    float*  aggb   = (float*) salloc((size_t)N * 64 * 4);
    float*  bufA   = (float*) salloc((size_t)N * 128 * 4);
    float*  bufB   = (float*) salloc((size_t)N * 64 * 4);
    double* sums   = (double*)salloc(768 * 8);
    float*  scale  = (float*) salloc(512);
    float*  shift  = (float*) salloc(512);
    float*  pooled = (float*) salloc((size_t)N_GRAPHS * 128 * 4);
    (void)ws_size;

    double* sums1 = sums, *sums2 = sums + 256, *sums3 = sums + 512;

    hipMemsetAsync(degi, 0, (size_t)N * 4, stream);
    hipMemsetAsync(sums, 0, 768 * 8, stream);
    hipMemsetAsync(pooled, 0, (size_t)N_GRAPHS * 128 * 4, stream);

    // ---- CSR build (by dst) ----
    const int nb = (N + 1023) / 1024;
    degi_kernel<<<(E + 255) / 256, 256, 0, stream>>>(dst, degi, E);
    scan1_kernel<<<nb, 256, 0, stream>>>(degi, offs, bsums, N);
    scan2_kernel<<<1, 64, 0, stream>>>(bsums, nb);
    scan3_kernel<<<(N + 255) / 256, 256, 0, stream>>>(offs, bsums, cursor, N, E);
    fill_kernel<<<(E + 255) / 256, 256, 0, stream>>>(src, dst, cursor, nbr, E);

    const int NL = (N + 255) / 256;

    // ---- layer 1: 2 -> 32, in x, out bufA ----
    agg2_kernel<<<NL, 256, 0, stream>>>((const float2*)x, offs, nbr, (float2*)aggb, N);
    linear_rt<2, 32><<<NL, 256, 0, stream>>>(x, aggb, degi, Wl1, bl1, Wr1, bufA, N);
    bn_stats_kernel<32><<<1024, 256, 0, stream>>>(bufA, sums1, N);
    bn_finalize_kernel<32><<<1, 32, 0, stream>>>(sums1, g1, be1, scale, shift, N);
    bn_apply_v4<32><<<(N * 32 / 4 + 255) / 256, 256, 0, stream>>>((float4*)bufA, (const float4*)scale, (const float4*)shift, N * 32 / 4);

    // ---- layer 2: 32 -> 64, in bufA, out bufB ----
    agg_csr_v4<32><<<(N + 31) / 32, dim3(8, 32), 0, stream>>>((const float4*)bufA, offs, nbr, (float4*)aggb, N);
    linear_rt<32, 64><<<NL, 256, 0, stream>>>(bufA, aggb, degi, Wl2, bl2, Wr2, bufB, N);
    bn_stats_kernel<64><<<1024, 256, 0, stream>>>(bufB, sums2, N);
    bn_finalize_kernel<64><<<1, 64, 0, stream>>>(sums2, g2, be2, scale, shift, N);
    bn_apply_v4<64><<<(N * 64 / 4 + 255) / 256, 256, 0, stream>>>((float4*)bufB, (const float4*)scale, (const float4*)shift, N * 64 / 4);

    // ---- layer 3: 64 -> 128, in bufB, out bufA ----
    agg_csr_v4<64><<<(N + 15) / 16, dim3(16, 16), 0, stream>>>((const float4*)bufB, offs, nbr, (float4*)aggb, N);
    linear_rt<64, 128><<<NL, 256, 0, stream>>>(bufB, aggb, degi, Wl3, bl3, Wr3, bufA, N);
    bn_stats_kernel<128><<<1024, 256, 0, stream>>>(bufA, sums3, N);
    bn_finalize_kernel<128><<<1, 128, 0, stream>>>(sums3, g3, be3, scale, shift, N);
    bn_apply_v4<128><<<(N * 128 / 4 + 255) / 256, 256, 0, stream>>>((float4*)bufA, (const float4*)scale, (const float4*)shift, N * 128 / 4);

    // ---- pool + head ----
    pool_partial<<<(N + 255) / 256, 128, 0, stream>>>(bufA, batch, pooled, N);
    pool_finalize<<<N_GRAPHS, 128, 0, stream>>>(pooled, batch, N);
    mlp_kernel<<<N_GRAPHS, 64, 0, stream>>>(pooled, Wf1, bf1, Wf2, bf2, (float*)d_out);
}

// Round 4
// 779.676 us; speedup vs baseline: 2.3132x; 1.1667x over previous
//
#include <hip/hip_runtime.h>

#define N_NODES 100000
#define N_GRAPHS 64
#define BN_EPS 1e-5

// ---------------- in-degree (int) ----------------
__global__ void degi_kernel(const int* __restrict__ dst, int* __restrict__ degi, int E) {
    int i = blockIdx.x * blockDim.x + threadIdx.x;
    if (i < E) atomicAdd(&degi[dst[i]], 1);
}

// ---------------- exclusive scan of degi -> offs (hierarchical) ----------------
__global__ void scan1_kernel(const int* __restrict__ degi, int* __restrict__ offs,
                             int* __restrict__ bsums, int N) {
    __shared__ int sh[256];
    int t = threadIdx.x;
    int base = blockIdx.x * 1024;
    int v[4]; int s = 0;
#pragma unroll
    for (int k = 0; k < 4; ++k) {
        int idx = base + t * 4 + k;
        v[k] = (idx < N) ? degi[idx] : 0;
        s += v[k];
    }
    sh[t] = s;
    __syncthreads();
    for (int st = 1; st < 256; st <<= 1) {
        int val = (t >= st) ? sh[t - st] : 0;
        __syncthreads();
        if (t >= st) sh[t] += val;
        __syncthreads();
    }
    int excl = (t > 0) ? sh[t - 1] : 0;
    if (t == 255) bsums[blockIdx.x] = sh[255];
    int run = excl;
#pragma unroll
    for (int k = 0; k < 4; ++k) {
        int idx = base + t * 4 + k;
        if (idx < N) offs[idx] = run;
        run += v[k];
    }
}

__global__ void scan2_kernel(int* __restrict__ bsums, int nb) {
    if (blockIdx.x == 0 && threadIdx.x == 0) {
        int run = 0;
        for (int i = 0; i < nb; ++i) { int v = bsums[i]; bsums[i] = run; run += v; }
    }
}

__global__ void scan3_kernel(int* __restrict__ offs, const int* __restrict__ bsums,
                             int* __restrict__ cursor, int N, int E) {
    int i = blockIdx.x * blockDim.x + threadIdx.x;
    if (i < N) {
        int v = offs[i] + bsums[i >> 10];
        offs[i] = v;
        cursor[i] = v;
    }
    if (i == 0) offs[N] = E;
}

__global__ void fill_kernel(const int* __restrict__ src, const int* __restrict__ dst,
                            int* __restrict__ cursor, int* __restrict__ nbr, int E) {
    int e = blockIdx.x * blockDim.x + threadIdx.x;
    if (e < E) {
        int p = atomicAdd(&cursor[dst[e]], 1);
        nbr[p] = src[e];
    }
}

// ---------------- CSR gather aggregation ----------------
__global__ void agg2_kernel(const float2* __restrict__ x, const int* __restrict__ offs,
                            const int* __restrict__ nbr, float2* __restrict__ agg, int N) {
    int n = blockIdx.x * blockDim.x + threadIdx.x;
    if (n >= N) return;
    int beg = offs[n], end = offs[n + 1];
    float ax = 0.f, ay = 0.f;
    for (int j = beg; j < end; ++j) {
        float2 v = x[nbr[j]];
        ax += v.x; ay += v.y;
    }
    agg[n] = make_float2(ax, ay);
}

template<int F>
__global__ void agg_csr_v4(const float4* __restrict__ x, const int* __restrict__ offs,
                           const int* __restrict__ nbr, float4* __restrict__ agg, int N) {
    const int FV = F / 4;
    const int NPB = 256 / FV;
    int n = blockIdx.x * NPB + threadIdx.y;
    if (n >= N) return;
    int f = threadIdx.x;
    int beg = offs[n], end = offs[n + 1];
    float4 acc = {0.f, 0.f, 0.f, 0.f};
    for (int j = beg; j < end; ++j) {
        int s = nbr[j];
        float4 v = x[(long long)s * FV + f];
        acc.x += v.x; acc.y += v.y; acc.z += v.z; acc.w += v.w;
    }
    agg[(long long)n * FV + f] = acc;
}

// ---------------- layer-1 linear (8B rows: naturally coalesced) ----------------
template<int DIN, int DOUT>
__global__ __launch_bounds__(256)
void linear_rt(const float* __restrict__ xin, const float* __restrict__ agg,
               const int* __restrict__ degi,
               const float* __restrict__ Wl, const float* __restrict__ bl,
               const float* __restrict__ Wr, float* __restrict__ hout, int N) {
    int n = blockIdx.x * 256 + threadIdx.x;
    if (n >= N) return;
    float invd = 1.0f / fmaxf((float)degi[n], 1.0f);
    const float* __restrict__ ar = agg + (size_t)n * DIN;
    const float* __restrict__ xp = xin + (size_t)n * DIN;
    float acc[DOUT];
#pragma unroll
    for (int j = 0; j < DOUT; ++j) acc[j] = bl[j];
    float2 av = *(const float2*)ar;
    float2 xv = *(const float2*)xp;
    float a[2] = {av.x * invd, av.y * invd};
    float xr[2] = {xv.x, xv.y};
#pragma unroll
    for (int k = 0; k < DIN; ++k) {
#pragma unroll
        for (int j = 0; j < DOUT; ++j)
            acc[j] += a[k] * Wl[k * DOUT + j] + xr[k] * Wr[k * DOUT + j];
    }
    float4* __restrict__ op = (float4*)(hout + (size_t)n * DOUT);
#pragma unroll
    for (int j4 = 0; j4 < DOUT / 4; ++j4)
        op[j4] = make_float4(acc[4*j4], acc[4*j4+1], acc[4*j4+2], acc[4*j4+3]);
}

// ---------------- LDS-staged tiled linear for layers 2/3 ----------------
// Block: 256 threads, TN nodes; thread = (node tn, j-group jg of JT=32).
// Stages agg & x tiles into LDS coalesced; weights via wave-uniform s_loads.
template<int DIN, int DOUT, int TN>
__global__ __launch_bounds__(256)
void linear_tiled(const float* __restrict__ xin, const float* __restrict__ agg,
                  const int* __restrict__ degi,
                  const float* __restrict__ Wl, const float* __restrict__ bl,
                  const float* __restrict__ Wr, float* __restrict__ hout, int N) {
    constexpr int JT = 32;
    constexpr int NG = DOUT / JT;
    static_assert(TN * NG == 256, "tile config");
    constexpr int STRIDE = DIN + 1;        // odd stride -> conflict-free LDS
    constexpr int DIV4 = DIN / 4;
    __shared__ float shA[TN * STRIDE];
    __shared__ float shX[TN * STRIDE];
    __shared__ float shD[TN];

    int n0 = blockIdx.x * TN;
    const float4* __restrict__ gA = (const float4*)(agg + (size_t)n0 * DIN);
    const float4* __restrict__ gX = (const float4*)(xin + (size_t)n0 * DIN);
    constexpr int NV4 = TN * DIN / 4;
#pragma unroll
    for (int it = 0; it < NV4 / 256; ++it) {
        int i = it * 256 + threadIdx.x;
        int row = i / DIV4;
        int col = (i % DIV4) * 4;
        float4 v = gA[i];
        float* p = &shA[row * STRIDE + col];
        p[0] = v.x; p[1] = v.y; p[2] = v.z; p[3] = v.w;
        float4 u = gX[i];
        float* q = &shX[row * STRIDE + col];
        q[0] = u.x; q[1] = u.y; q[2] = u.z; q[3] = u.w;
    }
    for (int i = threadIdx.x; i < TN; i += 256)
        shD[i] = 1.0f / fmaxf((float)degi[n0 + i], 1.0f);
    __syncthreads();

    int tn = threadIdx.x % TN;
    int jg = __builtin_amdgcn_readfirstlane(threadIdx.x / TN);
    int n = n0 + tn;

    float invd = shD[tn];
    float acc[JT];
#pragma unroll
    for (int j = 0; j < JT; ++j) acc[j] = bl[jg * JT + j];

#pragma unroll 4
    for (int k = 0; k < DIN; ++k) {
        float a  = shA[tn * STRIDE + k] * invd;
        float xv = shX[tn * STRIDE + k];
        const float* __restrict__ wlp = Wl + (size_t)k * DOUT + jg * JT;
        const float* __restrict__ wrp = Wr + (size_t)k * DOUT + jg * JT;
#pragma unroll
        for (int j = 0; j < JT; ++j)
            acc[j] += a * wlp[j] + xv * wrp[j];
    }

    if (n < N) {
        float4* __restrict__ op = (float4*)(hout + (size_t)n * DOUT + jg * JT);
#pragma unroll
        for (int j4 = 0; j4 < JT / 4; ++j4)
            op[j4] = make_float4(acc[4*j4], acc[4*j4+1], acc[4*j4+2], acc[4*j4+3]);
    }
}

// ---------------- BN stats (sum, sumsq per feature), fp64 accumulation ----------------
template<int F>
__global__ void bn_stats_kernel(const float* __restrict__ h, double* __restrict__ sums, int N) {
    const int R = 256 / F;
    int f = threadIdx.x & (F - 1);
    int r = threadIdx.x / F;
    float s = 0.f, sq = 0.f;
    for (int n = blockIdx.x * R + r; n < N; n += gridDim.x * R) {
        float v = h[(long long)n * F + f];
        s += v; sq += v * v;
    }
    __shared__ float sh[512];
    sh[threadIdx.x] = s;
    sh[256 + threadIdx.x] = sq;
    __syncthreads();
    for (int st = R / 2; st > 0; st >>= 1) {
        if (r < st) {
            sh[threadIdx.x] += sh[threadIdx.x + st * F];
            sh[256 + threadIdx.x] += sh[256 + threadIdx.x + st * F];
        }
        __syncthreads();
    }
    if (r == 0) {
        atomicAdd(&sums[f], (double)sh[f]);
        atomicAdd(&sums[F + f], (double)sh[256 + f]);
    }
}

template<int F>
__global__ void bn_finalize_kernel(const double* __restrict__ sums,
                                   const float* __restrict__ gamma, const float* __restrict__ beta,
                                   float* __restrict__ scale, float* __restrict__ shift, int N) {
    int f = threadIdx.x;
    if (f >= F) return;
    double mu  = sums[f] / (double)N;
    double var = sums[F + f] / (double)N - mu * mu;
    if (var < 0.0) var = 0.0;
    double sc = (double)gamma[f] / sqrt(var + BN_EPS);
    scale[f] = (float)sc;
    shift[f] = (float)((double)beta[f] - mu * sc);
}

template<int F>
__global__ void bn_apply_v4(float4* __restrict__ h, const float4* __restrict__ scale,
                            const float4* __restrict__ shift, int total4) {
    int i = blockIdx.x * blockDim.x + threadIdx.x;
    if (i >= total4) return;
    int fv = i & (F / 4 - 1);
    float4 v = h[i];
    float4 sc = scale[fv];
    float4 sf = shift[fv];
    v.x = fmaxf(v.x * sc.x + sf.x, 0.f);
    v.y = fmaxf(v.y * sc.y + sf.y, 0.f);
    v.z = fmaxf(v.z * sc.z + sf.z, 0.f);
    v.w = fmaxf(v.w * sc.w + sf.w, 0.f);
    h[i] = v;
}

// ---------------- parallel pool ----------------
__global__ void pool_partial(const float* __restrict__ h, const int* __restrict__ batch,
                             float* __restrict__ pooled, int N) {
    const int CH = 256;
    int n0 = blockIdx.x * CH;
    if (n0 >= N) return;
    int n1 = min(n0 + CH, N);
    int f = threadIdx.x;  // 128
    int g = batch[n0];
    float acc = 0.f;
    for (int n = n0; n < n1; ++n) {
        int bg = batch[n];
        if (bg != g) {
            atomicAdd(&pooled[g * 128 + f], acc);
            acc = 0.f;
            g = bg;
        }
        acc += h[(long long)n * 128 + f];
    }
    atomicAdd(&pooled[g * 128 + f], acc);
}

__global__ void pool_finalize(float* __restrict__ pooled, const int* __restrict__ batch, int N) {
    int g = blockIdx.x;
    int f = threadIdx.x;
    int lo = 0, hi = N;
    while (lo < hi) { int m = (lo + hi) >> 1; if (batch[m] < g) lo = m + 1; else hi = m; }
    int start = lo;
    hi = N;
    while (lo < hi) { int m = (lo + hi) >> 1; if (batch[m] < g + 1) lo = m + 1; else hi = m; }
    int cnt = lo - start;
    pooled[g * 128 + f] /= fmaxf((float)cnt, 1.0f);
}

// ---------------- head MLP ----------------
__global__ void mlp_kernel(const float* __restrict__ pooled,
                           const float* __restrict__ Wf1, const float* __restrict__ bf1,
                           const float* __restrict__ Wf2, const float* __restrict__ bf2,
                           float* __restrict__ out) {
    int g = blockIdx.x;
    int j = threadIdx.x;  // 64 hidden
    float hacc = bf1[j];
#pragma unroll 8
    for (int k = 0; k < 128; ++k) hacc += pooled[g * 128 + k] * Wf1[k * 64 + j];
    hacc = fmaxf(hacc, 0.f) * Wf2[j];
    for (int off = 32; off > 0; off >>= 1) hacc += __shfl_down(hacc, off);
    if (j == 0) out[g] = hacc + bf2[0];
}

extern "C" void kernel_launch(void* const* d_in, const int* in_sizes, int n_in,
                              void* d_out, int out_size, void* d_ws, size_t ws_size,
                              hipStream_t stream) {
    const float* x     = (const float*)d_in[0];
    const int*   ei    = (const int*)d_in[1];
    const int*   batch = (const int*)d_in[2];
    const float *Wl1=(const float*)d_in[3],  *bl1=(const float*)d_in[4],  *Wr1=(const float*)d_in[5];
    const float *g1 =(const float*)d_in[6],  *be1=(const float*)d_in[7];
    const float *Wl2=(const float*)d_in[8],  *bl2=(const float*)d_in[9],  *Wr2=(const float*)d_in[10];
    const float *g2 =(const float*)d_in[11], *be2=(const float*)d_in[12];
    const float *Wl3=(const float*)d_in[13], *bl3=(const float*)d_in[14], *Wr3=(const float*)d_in[15];
    const float *g3 =(const float*)d_in[16], *be3=(const float*)d_in[17];
    const float *Wf1=(const float*)d_in[18], *bf1=(const float*)d_in[19];
    const float *Wf2=(const float*)d_in[20], *bf2=(const float*)d_in[21];

    const int N = N_NODES;
    const int E = in_sizes[1] / 2;
    const int* src = ei;
    const int* dst = ei + E;

    // ---- workspace layout (256B-aligned) ----
    char* ws = (char*)d_ws;
    size_t off = 0;
    auto salloc = [&](size_t bytes) {
        void* p = ws + off;
        off += (bytes + 255) & ~(size_t)255;
        return p;
    };
    int*    degi   = (int*)   salloc((size_t)N * 4);
    int*    offs   = (int*)   salloc((size_t)(N + 1) * 4);
    int*    cursor = (int*)   salloc((size_t)N * 4);
    int*    bsums  = (int*)   salloc(512);
    int*    nbr    = (int*)   salloc((size_t)E * 4);
    float*  aggb   = (float*) salloc((size_t)N * 64 * 4);
    float*  bufA   = (float*) salloc((size_t)N * 128 * 4);
    float*  bufB   = (float*) salloc((size_t)N * 64 * 4);
    double* sums   = (double*)salloc(768 * 8);
    float*  scale  = (float*) salloc(512);
    float*  shift  = (float*) salloc(512);
    float*  pooled = (float*) salloc((size_t)N_GRAPHS * 128 * 4);
    (void)ws_size;

    double* sums1 = sums, *sums2 = sums + 256, *sums3 = sums + 512;

    hipMemsetAsync(degi, 0, (size_t)N * 4, stream);
    hipMemsetAsync(sums, 0, 768 * 8, stream);
    hipMemsetAsync(pooled, 0, (size_t)N_GRAPHS * 128 * 4, stream);

    // ---- CSR build (by dst) ----
    const int nb = (N + 1023) / 1024;
    degi_kernel<<<(E + 255) / 256, 256, 0, stream>>>(dst, degi, E);
    scan1_kernel<<<nb, 256, 0, stream>>>(degi, offs, bsums, N);
    scan2_kernel<<<1, 64, 0, stream>>>(bsums, nb);
    scan3_kernel<<<(N + 255) / 256, 256, 0, stream>>>(offs, bsums, cursor, N, E);
    fill_kernel<<<(E + 255) / 256, 256, 0, stream>>>(src, dst, cursor, nbr, E);

    const int NL = (N + 255) / 256;

    // ---- layer 1: 2 -> 32, in x, out bufA ----
    agg2_kernel<<<NL, 256, 0, stream>>>((const float2*)x, offs, nbr, (float2*)aggb, N);
    linear_rt<2, 32><<<NL, 256, 0, stream>>>(x, aggb, degi, Wl1, bl1, Wr1, bufA, N);
    bn_stats_kernel<32><<<1024, 256, 0, stream>>>(bufA, sums1, N);
    bn_finalize_kernel<32><<<1, 32, 0, stream>>>(sums1, g1, be1, scale, shift, N);
    bn_apply_v4<32><<<(N * 32 / 4 + 255) / 256, 256, 0, stream>>>((float4*)bufA, (const float4*)scale, (const float4*)shift, N * 32 / 4);

    // ---- layer 2: 32 -> 64, in bufA, out bufB ----
    agg_csr_v4<32><<<(N + 31) / 32, dim3(8, 32), 0, stream>>>((const float4*)bufA, offs, nbr, (float4*)aggb, N);
    linear_tiled<32, 64, 128><<<(N + 127) / 128, 256, 0, stream>>>(bufA, aggb, degi, Wl2, bl2, Wr2, bufB, N);
    bn_stats_kernel<64><<<1024, 256, 0, stream>>>(bufB, sums2, N);
    bn_finalize_kernel<64><<<1, 64, 0, stream>>>(sums2, g2, be2, scale, shift, N);
    bn_apply_v4<64><<<(N * 64 / 4 + 255) / 256, 256, 0, stream>>>((float4*)bufB, (const float4*)scale, (const float4*)shift, N * 64 / 4);

    // ---- layer 3: 64 -> 128, in bufB, out bufA ----
    agg_csr_v4<64><<<(N + 15) / 16, dim3(16, 16), 0, stream>>>((const float4*)bufB, offs, nbr, (float4*)aggb, N);
    linear_tiled<64, 128, 64><<<(N + 63) / 64, 256, 0, stream>>>(bufB, aggb, degi, Wl3, bl3, Wr3, bufA, N);
    bn_stats_kernel<128><<<1024, 256, 0, stream>>>(bufA, sums3, N);
    bn_finalize_kernel<128><<<1, 128, 0, stream>>>(sums3, g3, be3, scale, shift, N);
    bn_apply_v4<128><<<(N * 128 / 4 + 255) / 256, 256, 0, stream>>>((float4*)bufA, (const float4*)scale, (const float4*)shift, N * 128 / 4);

    // ---- pool + head ----
    pool_partial<<<(N + 255) / 256, 128, 0, stream>>>(bufA, batch, pooled, N);
    pool_finalize<<<N_GRAPHS, 128, 0, stream>>>(pooled, batch, N);
    mlp_kernel<<<N_GRAPHS, 64, 0, stream>>>(pooled, Wf1, bf1, Wf2, bf2, (float*)d_out);
}